// Round 11
// baseline (416.005 us; speedup 1.0000x reference)
//
#include <hip/hip_runtime.h>
#include <hip/hip_bf16.h>

#define P_TOTAL 160000
#define NPB     40000      // points per batch (B=4)
#define NCLS    13
#define TP      64         // points per block
#define NBLK    (P_TOTAL / TP)   // 2500

// R16 LDS strides: dword-stride must be ODD mod 32 to spread the 16-row
// A-fragment ds_read_b128 across 16 distinct banks (264 -> 132 dw = 4 mod 32 was
// a 4-way conflict; 266 -> 133 dw = 5 mod 32 is ~2-way = free per m136).
#define SA   266   // actbuf row stride (ushorts)
#define SC   138   // chunkbuf row stride (ushorts)
#define S0   42    // A0 row stride (ushorts)

typedef __attribute__((ext_vector_type(8))) short bf16x8;   // 8 bf16 in 4 VGPRs
typedef __attribute__((ext_vector_type(4))) float f32x4;

__device__ __forceinline__ ushort f2bf(float f) {
  union { float f; unsigned u; } v; v.f = f;
  return (ushort)((v.u + 0x8000) >> 16);   // round-to-nearest (ties away)
}

// ---------------- fused prep: transposes + WT1 + histogram ----------------
// R12 frag-linear for 16x16x32 MFMA B-tiles (16 n x 32 k, 1KB each):
//   off = ((n>>4)*(K>>5) + (k>>5))*512 + (n&15)*32 + (k&31)
__device__ __forceinline__ void transpose_tile(const float* __restrict__ src,
                                               ushort* __restrict__ dst,
                                               int K, int N, int tile, ushort (*t)[33]) {
  int ntx = N >> 5;
  int n0 = (tile % ntx) << 5, k0 = (tile / ntx) << 5;
  int KB = K >> 5;
  int c = threadIdx.x & 31, r = threadIdx.x >> 5;   // 8 rows of 32
  #pragma unroll
  for (int rr = 0; rr < 32; rr += 8)
    t[r + rr][c] = f2bf(src[(k0 + r + rr) * N + n0 + c]);
  __syncthreads();
  #pragma unroll
  for (int rr = 0; rr < 32; rr += 8) {
    int n = n0 + r + rr, k = k0 + c;     // t[c][r+rr] = src[k][n]
    dst[((n >> 4) * KB + (k >> 5)) * 512 + (n & 15) * 32 + (k & 31)] = t[c][r + rr];
  }
}

__global__ void prep_all_kernel(const float* __restrict__ We1, const float* __restrict__ We2,
                                const float* __restrict__ W1,  const float* __restrict__ W2,
                                const int* __restrict__ y,
                                ushort* __restrict__ WT1, ushort* __restrict__ WT2,
                                ushort* __restrict__ WT3, ushort* __restrict__ WT4,
                                int* __restrict__ counts) {
  __shared__ ushort t[32][33];
  __shared__ int h[NCLS];
  int b = blockIdx.x, tid = threadIdx.x;
  if (b < 128)       transpose_tile(We2, WT2, 256, 512, b, t);
  else if (b < 256)  transpose_tile(W1,  WT3, 512, 256, b - 128, t);
  else if (b < 288)  transpose_tile(W2,  WT4, 256, 128, b - 256, t);
  else if (b == 288) {
    for (int i = tid; i < 8192; i += 256) {        // WT1: KB=1 -> frag-linear
      int n = i >> 5, k = i & 31;
      WT1[(n >> 4) * 512 + (n & 15) * 32 + k] = (k < 7) ? f2bf(We1[k * 256 + n]) : (ushort)0;
    }
  } else {
    if (tid < NCLS) h[tid] = 0;
    __syncthreads();
    for (int i = (b - 289) * 256 + tid; i < P_TOTAL; i += 127 * 256)
      atomicAdd(&h[y[i]], 1);
    __syncthreads();
    if (tid < NCLS) atomicAdd(&counts[tid], h[tid]);
  }
}

// ---------------- fused MLP + norm + output + class sums + last-block finalize ----------------
// Layouts (measured m89/m91): A[m=lane&15][k=quad*8+j]; B[n=lane&15][k=quad*8+j];
// C/D: col=lane&15, row=quad*4+reg.
// Ledger: R4 spill; R6 LDS-diet neutral (reg-capped, 2 blocks/CU); R7 remap regress;
//   R9 rolled prefetch regress; R10 setprio+LDS-csum regress; R12 frag-linear B WIN
//   261->198 (B-gather was exposed latency); R13 32x32 ILP1 regress 198->267 (MFMA
//   chain latency); R14 +ILP2 partial 235; R15 TP=32 regress 198->291 (2x B traffic,
//   conflicts back, occupancy flat). Structural space exhausted — R12 is the base.
// R16 (this round): odd-dword LDS strides ONLY (264->266, 136->138, 40->42).
//   R12's A-fragment ds_reads were 4-way bank conflicted (stride = 4 mod 32, 1.8e7
//   conflict-cycles = ~7.5% of block wall, directly exposed in a dep-stalled kernel).
//   Odd stride (5 mod 32) -> 16 distinct banks, ~2-way with quad overlap = free.
//   Pure constants: no loop/schedule/layout changes (the only edit class that has
//   ever won on this kernel).
__global__ __launch_bounds__(512, 4) void main_kernel(
    const float* __restrict__ pos, const float* __restrict__ x, const int* __restrict__ y,
    const float* __restrict__ be1, const float* __restrict__ be2,
    const float* __restrict__ b1,  const float* __restrict__ b2,
    const ushort* __restrict__ WT1, const ushort* __restrict__ WT2,
    const ushort* __restrict__ WT3, const ushort* __restrict__ WT4,
    const int* __restrict__ counts, float* __restrict__ gsums, int* __restrict__ done,
    const float* __restrict__ prior, float* __restrict__ out) {
  __shared__ ushort actbuf[TP * SA];        // 34048 B: act1 [64][256 @stride 266], later act3
  __shared__ ushort chunkbuf[TP * SC];      // 17664 B: A0 (stride 42) -> act2 chunks (stride 138)
                                            //   post-L3 dead -> aliased as part[8*TP] f32
  __shared__ float  inv_norm[TP];
  __shared__ float  lbl_eff[TP];
  __shared__ int    lbl[TP];
  __shared__ float  invn[NCLS];
  __shared__ int    is_last;

  const int tid  = threadIdx.x;
  const int wave = tid >> 6, lane = tid & 63;
  const int quad = lane >> 4, mrow = lane & 15;
  const long p0 = (long)blockIdx.x * TP;   // 40000 % 64 == 0: block never spans batches
  const int bb = (int)(p0 / NPB);
  const int n0 = (int)(p0 % NPB);
  const f32x4 zero = {0.f, 0.f, 0.f, 0.f};

  // ---- stage A0 = [x(4) | pos(3) | 0...] bf16, stride S0, into chunkbuf ----
  for (int i = tid; i < TP * S0; i += 512) {
    int r = i / S0, k = i - r * S0;
    float v = 0.f;
    if (k < 4)      v = x[(bb * 4 + k) * NPB + n0 + r];
    else if (k < 7) v = pos[(p0 + r) * 3 + (k - 4)];
    chunkbuf[r * S0 + k] = f2bf(v);
  }
  if (tid < TP) lbl[tid] = y[p0 + tid];
  __syncthreads();                                            // B1

  // ---- L1: [64x32] @ WT1 -> act1; wave cols wave*32 + nt*16 ----
  {
    f32x4 acc1[4][2];
    #pragma unroll
    for (int mt = 0; mt < 4; mt++) { acc1[mt][0] = zero; acc1[mt][1] = zero; }
    const int kl = quad << 3;
    bf16x8 af[4], bw[2];
    #pragma unroll
    for (int mt = 0; mt < 4; mt++)
      af[mt] = *(const bf16x8*)(&chunkbuf[0] + (mt * 16 + mrow) * S0 + kl);
    #pragma unroll
    for (int nt = 0; nt < 2; nt++)   // frag-linear: nb = wave*2+nt, KB=1
      bw[nt] = *(const bf16x8*)(WT1 + (wave * 2 + nt) * 512 + mrow * 32 + kl);
    #pragma unroll
    for (int nt = 0; nt < 2; nt++)
      #pragma unroll
      for (int mt = 0; mt < 4; mt++)
        acc1[mt][nt] = __builtin_amdgcn_mfma_f32_16x16x32_bf16(af[mt], bw[nt], acc1[mt][nt], 0, 0, 0);
    #pragma unroll
    for (int nt = 0; nt < 2; nt++) {
      int n = wave * 32 + nt * 16 + mrow;
      float bv = be1[n];
      #pragma unroll
      for (int mt = 0; mt < 4; mt++)
        #pragma unroll
        for (int r = 0; r < 4; r++)
          actbuf[(mt * 16 + quad * 4 + r) * SA + n] = f2bf(fmaxf(acc1[mt][nt][r] + bv, 0.f));
    }
  }
  __syncthreads();                                            // B2 (also covers A0 readers)

  // ---- fused L2+L3, single chunk buffer, two barriers per chunk ----
  // Hazard: cb writes of chunk c wait (via the if(c) barrier) for all waves' L3(c-1)
  // cb reads. For c=0 the A0 reads are covered by B2.
  f32x4 acc3[4][2];
  #pragma unroll
  for (int mt = 0; mt < 4; mt++) { acc3[mt][0] = zero; acc3[mt][1] = zero; }

  ushort* const cb = &chunkbuf[0];
  for (int c = 0; c < 4; c++) {
    // L2: wave computes act2 chunk-local cols [wave*16, +16); no cb access
    f32x4 acc2[4];
    #pragma unroll
    for (int mt = 0; mt < 4; mt++) acc2[mt] = zero;
    #pragma unroll
    for (int ks = 0; ks < 8; ks++) {
      const int kl = ks * 32 + (quad << 3);
      bf16x8 af[4];
      #pragma unroll
      for (int mt = 0; mt < 4; mt++)
        af[mt] = *(const bf16x8*)(actbuf + (mt * 16 + mrow) * SA + kl);
      // frag-linear WT2: nb = c*8+wave, KB=8, kb = ks
      bf16x8 bw = *(const bf16x8*)(WT2 + ((c * 8 + wave) * 8 + ks) * 512 + mrow * 32 + (quad << 3));
      #pragma unroll
      for (int mt = 0; mt < 4; mt++)
        acc2[mt] = __builtin_amdgcn_mfma_f32_16x16x32_bf16(af[mt], bw, acc2[mt], 0, 0, 0);
    }
    if (c) __syncthreads();                                   // waves done L3(c-1) cb reads
    {
      int lc = wave * 16 + mrow;            // chunk-local col
      float bv = be2[c * 128 + lc];
      #pragma unroll
      for (int mt = 0; mt < 4; mt++)
        #pragma unroll
        for (int r = 0; r < 4; r++)
          cb[(mt * 16 + quad * 4 + r) * SC + lc] = f2bf(fmaxf(acc2[mt][r] + bv, 0.f));
    }
    __syncthreads();                                          // cb ready
    // L3 accumulate over this chunk's 128 k values; wave cols wave*32 + nt*16
    #pragma unroll
    for (int ks = 0; ks < 4; ks++) {
      const int kl = ks * 32 + (quad << 3);
      bf16x8 af[4], bw[2];
      #pragma unroll
      for (int mt = 0; mt < 4; mt++)
        af[mt] = *(const bf16x8*)(cb + (mt * 16 + mrow) * SC + kl);
      // frag-linear WT3: nb = wave*2+nt, KB=16, kb = c*4+ks
      #pragma unroll
      for (int nt = 0; nt < 2; nt++)
        bw[nt] = *(const bf16x8*)(WT3 + ((wave * 2 + nt) * 16 + c * 4 + ks) * 512 + mrow * 32 + (quad << 3));
      #pragma unroll
      for (int nt = 0; nt < 2; nt++)
        #pragma unroll
        for (int mt = 0; mt < 4; mt++)
          acc3[mt][nt] = __builtin_amdgcn_mfma_f32_16x16x32_bf16(af[mt], bw[nt], acc3[mt][nt], 0, 0, 0);
    }
  }

  // ---- L3 epilogue -> act3 into actbuf ----
  // No barrier needed before these writes: last actbuf reads were the L2(3) compute,
  // which all waves finished before the pre-L3(3) barrier.
  #pragma unroll
  for (int nt = 0; nt < 2; nt++) {
    int n = wave * 32 + nt * 16 + mrow;
    float bv = b1[n];
    #pragma unroll
    for (int mt = 0; mt < 4; mt++)
      #pragma unroll
      for (int r = 0; r < 4; r++)
        actbuf[(mt * 16 + quad * 4 + r) * SA + n] = f2bf(fmaxf(acc3[mt][nt][r] + bv, 0.f));
  }
  __syncthreads();                                            // B7

  // chunkbuf is dead from here (all waves past their last cb reads, pre-B7):
  // alias the norm-partial buffer into it.
  float* const part = (float*)&chunkbuf[0];                   // 8*TP floats = 2048 B

  // ---- L4: wave col = wave*16 + mrow; feat stays in registers ----
  f32x4 acc4[4];
  #pragma unroll
  for (int mt = 0; mt < 4; mt++) acc4[mt] = zero;
  #pragma unroll
  for (int ks = 0; ks < 8; ks++) {
    const int kl = ks * 32 + (quad << 3);
    bf16x8 af[4];
    #pragma unroll
    for (int mt = 0; mt < 4; mt++)
      af[mt] = *(const bf16x8*)(actbuf + (mt * 16 + mrow) * SA + kl);
    // frag-linear WT4: nb = wave, KB=8, kb = ks
    bf16x8 bw = *(const bf16x8*)(WT4 + (wave * 8 + ks) * 512 + mrow * 32 + (quad << 3));
    #pragma unroll
    for (int mt = 0; mt < 4; mt++)
      acc4[mt] = __builtin_amdgcn_mfma_f32_16x16x32_bf16(af[mt], bw, acc4[mt], 0, 0, 0);
  }
  const int col = wave * 16 + mrow;
  float val[4][4];
  {
    float bv = b2[col];
    #pragma unroll
    for (int mt = 0; mt < 4; mt++)
      #pragma unroll
      for (int r = 0; r < 4; r++)
        val[mt][r] = fmaxf(acc4[mt][r] + bv, 0.f);
  }

  // ---- row-norm partials via quad shfl ----
  #pragma unroll
  for (int mt = 0; mt < 4; mt++)
    #pragma unroll
    for (int r = 0; r < 4; r++) {
      float s = val[mt][r] * val[mt][r];
      s += __shfl_xor(s, 1);  s += __shfl_xor(s, 2);
      s += __shfl_xor(s, 4);  s += __shfl_xor(s, 8);
      if (mrow == 0) part[wave * TP + mt * 16 + quad * 4 + r] = s;
    }
  __syncthreads();                                            // B8
  if (tid < TP) {
    float ss = 0.f;
    #pragma unroll
    for (int w = 0; w < 8; w++) ss += part[w * TP + tid];
    inv_norm[tid] = 1.f / fmaxf(sqrtf(ss), 1e-12f);
    int l = lbl[tid];
    lbl_eff[tid] = (counts[l] >= 256) ? (float)l : -1.f;   // MIN_PTS gate
  }
  __syncthreads();                                            // B9

  // ---- store current_prior from regs + per-class sums ----
  float a[NCLS];
  #pragma unroll
  for (int cc = 0; cc < NCLS; cc++) a[cc] = 0.f;
  #pragma unroll
  for (int mt = 0; mt < 4; mt++)
    #pragma unroll
    for (int r = 0; r < 4; r++) {
      int R = mt * 16 + quad * 4 + r;
      float vn = val[mt][r] * inv_norm[R];
      out[(p0 + R) * 129 + col] = vn;
      int cls = lbl[R];
      #pragma unroll
      for (int cc = 0; cc < NCLS; cc++) a[cc] += (cls == cc) ? vn : 0.f;
    }
  if (tid < TP) out[(p0 + tid) * 129 + 128] = lbl_eff[tid];
  #pragma unroll
  for (int cc = 0; cc < NCLS; cc++) {
    a[cc] += __shfl_xor(a[cc], 16);
    a[cc] += __shfl_xor(a[cc], 32);
  }
  if (quad == 0)
    #pragma unroll
    for (int cc = 0; cc < NCLS; cc++) atomicAdd(&gsums[cc * 128 + col], a[cc]);

  // ---- last block finalizes the EMA prior (saves a dispatch) ----
  // Ordering: __syncthreads drains vmcnt(0) -> this block's gsums atomics have
  // completed at the device coherence point before the done increment.
  __syncthreads();                                            // B10
  if (tid == 0) {
    int old = atomicAdd(done, 1);
    is_last = (old == NBLK - 1);
  }
  __syncthreads();
  if (!is_last) return;

  float* vbuf = (float*)actbuf;            // actbuf dead; 6656 B needed
  for (int i = tid; i < NCLS * 128; i += 512) {
    float g = atomicAdd(&gsums[i], 0.f);   // coherent device-scope read
    int cls = i >> 7;
    int cnt = counts[cls];
    float mean = g / fmaxf((float)cnt, 1.f);
    float pr = prior[i];
    float cur = (cnt >= 256) ? mean : pr;
    vbuf[i] = 0.999f * pr + 0.001f * cur;
  }
  __syncthreads();
  if (tid < NCLS) {
    float s = 0.f;
    for (int c = 0; c < 128; c++) { float t = vbuf[tid * 128 + c]; s += t * t; }
    invn[tid] = 1.f / fmaxf(sqrtf(s), 1e-12f);
  }
  __syncthreads();
  for (int i = tid; i < NCLS * 128; i += 512)
    out[(long)P_TOTAL * 129 + i] = vbuf[i] * invn[i >> 7];
}

extern "C" void kernel_launch(void* const* d_in, const int* in_sizes, int n_in,
                              void* d_out, int out_size, void* d_ws, size_t ws_size,
                              hipStream_t stream) {
  const float* pos   = (const float*)d_in[0];
  const float* x     = (const float*)d_in[1];
  const int*   y     = (const int*)  d_in[2];
  const float* We1   = (const float*)d_in[3];
  const float* be1   = (const float*)d_in[4];
  const float* We2   = (const float*)d_in[5];
  const float* be2   = (const float*)d_in[6];
  const float* W1    = (const float*)d_in[7];
  const float* b1    = (const float*)d_in[8];
  const float* W2    = (const float*)d_in[9];
  const float* b2    = (const float*)d_in[10];
  const float* prior = (const float*)d_in[11];
  float* out = (float*)d_out;

  char* ws = (char*)d_ws;
  int*    counts = (int*)   (ws + 0);        //    64 B
  float*  gsums  = (float*) (ws + 256);      //  6656 B
  int*    done   = (int*)   (ws + 7168);     //     4 B
  ushort* WT1    = (ushort*)(ws + 8192);     // 16384 B  frag-linear [16 nb][512]
  ushort* WT2    = (ushort*)(ws + 24576);    // 262144 B frag-linear [32 nb][8 kb][512]
  ushort* WT3    = (ushort*)(ws + 286720);   // 262144 B frag-linear [16 nb][16 kb][512]
  ushort* WT4    = (ushort*)(ws + 548864);   // 65536 B  frag-linear [8 nb][8 kb][512]

  hipMemsetAsync(ws, 0, 8192, stream);       // counts + gsums + done
  prep_all_kernel<<<416, 256, 0, stream>>>(We1, We2, W1, W2, y, WT1, WT2, WT3, WT4, counts);
  main_kernel    <<<NBLK, 512, 0, stream>>>(pos, x, y, be1, be2, b1, b2,
                                            WT1, WT2, WT3, WT4, counts, gsums, done, prior, out);
}

// Round 12
// 279.970 us; speedup vs baseline: 1.4859x; 1.4859x over previous
//
#include <hip/hip_runtime.h>
#include <hip/hip_bf16.h>

#define P_TOTAL 160000
#define NPB     40000      // points per batch (B=4)
#define NCLS    13
#define TP      64         // points per block
#define NBLK    (P_TOTAL / TP)   // 2500

typedef __attribute__((ext_vector_type(8))) short bf16x8;   // 8 bf16 in 4 VGPRs
typedef __attribute__((ext_vector_type(4))) float f32x4;

__device__ __forceinline__ ushort f2bf(float f) {
  union { float f; unsigned u; } v; v.f = f;
  return (ushort)((v.u + 0x8000) >> 16);   // round-to-nearest (ties away)
}

// ---------------- fused prep: transposes + WT1 + histogram ----------------
// R12 frag-linear: for each (nb = n>>4, kb = k>>5) 16x32 MFMA B-tile, the tile is
// contiguous 1KB: off = ((nb*KB + kb)*16 + (n&15))*32 + (k&31). A wave's B-fragment
// load is lane-linear 16B/lane (4 sequential cache lines) instead of a 16-row x
// 512B-strided gather. This was the session's one big win (261->198us main).
__device__ __forceinline__ void transpose_tile(const float* __restrict__ src,
                                               ushort* __restrict__ dst,
                                               int K, int N, int tile, ushort (*t)[33]) {
  int ntx = N >> 5;
  int n0 = (tile % ntx) << 5, k0 = (tile / ntx) << 5;
  int KB = K >> 5;
  int c = threadIdx.x & 31, r = threadIdx.x >> 5;   // 8 rows of 32
  #pragma unroll
  for (int rr = 0; rr < 32; rr += 8)
    t[r + rr][c] = f2bf(src[(k0 + r + rr) * N + n0 + c]);
  __syncthreads();
  #pragma unroll
  for (int rr = 0; rr < 32; rr += 8) {
    int n = n0 + r + rr, k = k0 + c;     // t[c][r+rr] = src[k][n]
    dst[((n >> 4) * KB + (k >> 5)) * 512 + (n & 15) * 32 + (k & 31)] = t[c][r + rr];
  }
}

__global__ void prep_all_kernel(const float* __restrict__ We1, const float* __restrict__ We2,
                                const float* __restrict__ W1,  const float* __restrict__ W2,
                                const int* __restrict__ y,
                                ushort* __restrict__ WT1, ushort* __restrict__ WT2,
                                ushort* __restrict__ WT3, ushort* __restrict__ WT4,
                                int* __restrict__ counts) {
  __shared__ ushort t[32][33];
  __shared__ int h[NCLS];
  int b = blockIdx.x, tid = threadIdx.x;
  if (b < 128)       transpose_tile(We2, WT2, 256, 512, b, t);
  else if (b < 256)  transpose_tile(W1,  WT3, 512, 256, b - 128, t);
  else if (b < 288)  transpose_tile(W2,  WT4, 256, 128, b - 256, t);
  else if (b == 288) {
    for (int i = tid; i < 8192; i += 256) {        // WT1: KB=1 -> frag-linear
      int n = i >> 5, k = i & 31;
      WT1[(n >> 4) * 512 + (n & 15) * 32 + k] = (k < 7) ? f2bf(We1[k * 256 + n]) : (ushort)0;
    }
  } else {
    if (tid < NCLS) h[tid] = 0;
    __syncthreads();
    for (int i = (b - 289) * 256 + tid; i < P_TOTAL; i += 127 * 256)
      atomicAdd(&h[y[i]], 1);
    __syncthreads();
    if (tid < NCLS) atomicAdd(&counts[tid], h[tid]);
  }
}

// ---------------- fused MLP + norm + output + class sums + last-block finalize ----------------
// Layouts (measured m89/m91): A[m=lane&15][k=quad*8+j]; B[n=lane&15][k=quad*8+j];
// C/D: col=lane&15, row=quad*4+reg.
// FINAL (R17 = exact R12, the session best: main 198us, total 285.7us).
// Session ledger — why this exact form:
//   R4  (512,6) launch bound        -> VGPR spill, 9x HBM        REGRESS
//   R5  XOR-swizzled LDS addressing -> live temps -> spill        REGRESS
//   R6  LDS 71.6->52.2KB            -> occupancy flat (reg-capped) NEUTRAL
//   R7  L2/L4 wave remap + LDS csum -> 418us                      REGRESS
//   R9  rolled B-prefetch unroll-1  -> 272us (VALU overhead)      REGRESS
//   R10 setprio + LDS-atomic csum   -> 334us                      REGRESS
//   R12 frag-linear B layout        -> 261->198us                 ***WIN***
//   R13 32x32 MFMA (ILP1 chains)    -> 267us (dep-chain stall)    REGRESS
//   R14 32x32 + ILP2 split          -> 235us                      REGRESS vs R12
//   R15 TP=32 4-wave blocks         -> 291us (2x B traffic)       REGRESS
//   R16 odd-dword LDS strides       -> 327us (conflicts UP; model wrong for b128)
// Conclusion: 198us is a sharp codegen local optimum. Not a pipe roofline
// (MfmaUtil 21%, VALU 32%, HBM 6.6%) — residual is dep-stall at 2 lockstep
// blocks/CU, reg-bucket-pinned. Every structural escape attempt regressed 20-65%.
__global__ __launch_bounds__(512, 4) void main_kernel(
    const float* __restrict__ pos, const float* __restrict__ x, const int* __restrict__ y,
    const float* __restrict__ be1, const float* __restrict__ be2,
    const float* __restrict__ b1,  const float* __restrict__ b2,
    const ushort* __restrict__ WT1, const ushort* __restrict__ WT2,
    const ushort* __restrict__ WT3, const ushort* __restrict__ WT4,
    const int* __restrict__ counts, float* __restrict__ gsums, int* __restrict__ done,
    const float* __restrict__ prior, float* __restrict__ out) {
  __shared__ ushort actbuf[TP * 264];       // 33792 B: act1 [64][256+8], later act3
  __shared__ ushort chunkbuf[TP * 136];     // 17408 B: A0 (stride 40) -> act2 chunks (single buf)
                                            //   post-L3 it is dead -> aliased as part[8*TP] f32
  __shared__ float  inv_norm[TP];
  __shared__ float  lbl_eff[TP];
  __shared__ int    lbl[TP];
  __shared__ float  invn[NCLS];
  __shared__ int    is_last;

  const int tid  = threadIdx.x;
  const int wave = tid >> 6, lane = tid & 63;
  const int quad = lane >> 4, mrow = lane & 15;
  const long p0 = (long)blockIdx.x * TP;   // 40000 % 64 == 0: block never spans batches
  const int bb = (int)(p0 / NPB);
  const int n0 = (int)(p0 % NPB);
  const f32x4 zero = {0.f, 0.f, 0.f, 0.f};

  // ---- stage A0 = [x(4) | pos(3) | 0...] bf16, stride 40, into chunkbuf ----
  for (int i = tid; i < TP * 40; i += 512) {
    int r = i / 40, k = i - r * 40;
    float v = 0.f;
    if (k < 4)      v = x[(bb * 4 + k) * NPB + n0 + r];
    else if (k < 7) v = pos[(p0 + r) * 3 + (k - 4)];
    chunkbuf[r * 40 + k] = f2bf(v);
  }
  if (tid < TP) lbl[tid] = y[p0 + tid];
  __syncthreads();                                            // B1

  // ---- L1: [64x32] @ WT1 -> act1; wave cols wave*32 + nt*16 ----
  {
    f32x4 acc1[4][2];
    #pragma unroll
    for (int mt = 0; mt < 4; mt++) { acc1[mt][0] = zero; acc1[mt][1] = zero; }
    const int kl = quad << 3;
    bf16x8 af[4], bw[2];
    #pragma unroll
    for (int mt = 0; mt < 4; mt++)
      af[mt] = *(const bf16x8*)(&chunkbuf[0] + (mt * 16 + mrow) * 40 + kl);
    #pragma unroll
    for (int nt = 0; nt < 2; nt++)   // frag-linear: nb = wave*2+nt, KB=1
      bw[nt] = *(const bf16x8*)(WT1 + (wave * 2 + nt) * 512 + mrow * 32 + kl);
    #pragma unroll
    for (int nt = 0; nt < 2; nt++)
      #pragma unroll
      for (int mt = 0; mt < 4; mt++)
        acc1[mt][nt] = __builtin_amdgcn_mfma_f32_16x16x32_bf16(af[mt], bw[nt], acc1[mt][nt], 0, 0, 0);
    #pragma unroll
    for (int nt = 0; nt < 2; nt++) {
      int n = wave * 32 + nt * 16 + mrow;
      float bv = be1[n];
      #pragma unroll
      for (int mt = 0; mt < 4; mt++)
        #pragma unroll
        for (int r = 0; r < 4; r++)
          actbuf[(mt * 16 + quad * 4 + r) * 264 + n] = f2bf(fmaxf(acc1[mt][nt][r] + bv, 0.f));
    }
  }
  __syncthreads();                                            // B2 (also covers A0 readers)

  // ---- fused L2+L3, single chunk buffer, two barriers per chunk ----
  // Hazard: cb writes of chunk c wait (via the if(c) barrier) for all waves' L3(c-1)
  // cb reads. For c=0 the A0 reads are covered by B2.
  f32x4 acc3[4][2];
  #pragma unroll
  for (int mt = 0; mt < 4; mt++) { acc3[mt][0] = zero; acc3[mt][1] = zero; }

  ushort* const cb = &chunkbuf[0];
  for (int c = 0; c < 4; c++) {
    // L2: wave computes act2 chunk-local cols [wave*16, +16); no cb access
    f32x4 acc2[4];
    #pragma unroll
    for (int mt = 0; mt < 4; mt++) acc2[mt] = zero;
    #pragma unroll
    for (int ks = 0; ks < 8; ks++) {
      const int kl = ks * 32 + (quad << 3);
      bf16x8 af[4];
      #pragma unroll
      for (int mt = 0; mt < 4; mt++)
        af[mt] = *(const bf16x8*)(actbuf + (mt * 16 + mrow) * 264 + kl);
      // frag-linear WT2: nb = c*8+wave, KB=8, kb = ks
      bf16x8 bw = *(const bf16x8*)(WT2 + ((c * 8 + wave) * 8 + ks) * 512 + mrow * 32 + (quad << 3));
      #pragma unroll
      for (int mt = 0; mt < 4; mt++)
        acc2[mt] = __builtin_amdgcn_mfma_f32_16x16x32_bf16(af[mt], bw, acc2[mt], 0, 0, 0);
    }
    if (c) __syncthreads();                                   // waves done L3(c-1) cb reads
    {
      int lc = wave * 16 + mrow;            // chunk-local col
      float bv = be2[c * 128 + lc];
      #pragma unroll
      for (int mt = 0; mt < 4; mt++)
        #pragma unroll
        for (int r = 0; r < 4; r++)
          cb[(mt * 16 + quad * 4 + r) * 136 + lc] = f2bf(fmaxf(acc2[mt][r] + bv, 0.f));
    }
    __syncthreads();                                          // cb ready
    // L3 accumulate over this chunk's 128 k values; wave cols wave*32 + nt*16
    #pragma unroll
    for (int ks = 0; ks < 4; ks++) {
      const int kl = ks * 32 + (quad << 3);
      bf16x8 af[4], bw[2];
      #pragma unroll
      for (int mt = 0; mt < 4; mt++)
        af[mt] = *(const bf16x8*)(cb + (mt * 16 + mrow) * 136 + kl);
      // frag-linear WT3: nb = wave*2+nt, KB=16, kb = c*4+ks
      #pragma unroll
      for (int nt = 0; nt < 2; nt++)
        bw[nt] = *(const bf16x8*)(WT3 + ((wave * 2 + nt) * 16 + c * 4 + ks) * 512 + mrow * 32 + (quad << 3));
      #pragma unroll
      for (int nt = 0; nt < 2; nt++)
        #pragma unroll
        for (int mt = 0; mt < 4; mt++)
          acc3[mt][nt] = __builtin_amdgcn_mfma_f32_16x16x32_bf16(af[mt], bw[nt], acc3[mt][nt], 0, 0, 0);
    }
  }

  // ---- L3 epilogue -> act3 into actbuf ----
  // No barrier needed before these writes: last actbuf reads were the L2(3) compute,
  // which all waves finished before the pre-L3(3) barrier.
  #pragma unroll
  for (int nt = 0; nt < 2; nt++) {
    int n = wave * 32 + nt * 16 + mrow;
    float bv = b1[n];
    #pragma unroll
    for (int mt = 0; mt < 4; mt++)
      #pragma unroll
      for (int r = 0; r < 4; r++)
        actbuf[(mt * 16 + quad * 4 + r) * 264 + n] = f2bf(fmaxf(acc3[mt][nt][r] + bv, 0.f));
  }
  __syncthreads();                                            // B7

  // chunkbuf is dead from here (all waves past their last cb reads, pre-B7):
  // alias the norm-partial buffer into it.
  float* const part = (float*)&chunkbuf[0];                   // 8*TP floats = 2048 B

  // ---- L4: wave col = wave*16 + mrow; feat stays in registers ----
  f32x4 acc4[4];
  #pragma unroll
  for (int mt = 0; mt < 4; mt++) acc4[mt] = zero;
  #pragma unroll
  for (int ks = 0; ks < 8; ks++) {
    const int kl = ks * 32 + (quad << 3);
    bf16x8 af[4];
    #pragma unroll
    for (int mt = 0; mt < 4; mt++)
      af[mt] = *(const bf16x8*)(actbuf + (mt * 16 + mrow) * 264 + kl);
    // frag-linear WT4: nb = wave, KB=8, kb = ks
    bf16x8 bw = *(const bf16x8*)(WT4 + (wave * 8 + ks) * 512 + mrow * 32 + (quad << 3));
    #pragma unroll
    for (int mt = 0; mt < 4; mt++)
      acc4[mt] = __builtin_amdgcn_mfma_f32_16x16x32_bf16(af[mt], bw, acc4[mt], 0, 0, 0);
  }
  const int col = wave * 16 + mrow;
  float val[4][4];
  {
    float bv = b2[col];
    #pragma unroll
    for (int mt = 0; mt < 4; mt++)
      #pragma unroll
      for (int r = 0; r < 4; r++)
        val[mt][r] = fmaxf(acc4[mt][r] + bv, 0.f);
  }

  // ---- row-norm partials via quad shfl ----
  #pragma unroll
  for (int mt = 0; mt < 4; mt++)
    #pragma unroll
    for (int r = 0; r < 4; r++) {
      float s = val[mt][r] * val[mt][r];
      s += __shfl_xor(s, 1);  s += __shfl_xor(s, 2);
      s += __shfl_xor(s, 4);  s += __shfl_xor(s, 8);
      if (mrow == 0) part[wave * TP + mt * 16 + quad * 4 + r] = s;
    }
  __syncthreads();                                            // B8
  if (tid < TP) {
    float ss = 0.f;
    #pragma unroll
    for (int w = 0; w < 8; w++) ss += part[w * TP + tid];
    inv_norm[tid] = 1.f / fmaxf(sqrtf(ss), 1e-12f);
    int l = lbl[tid];
    lbl_eff[tid] = (counts[l] >= 256) ? (float)l : -1.f;   // MIN_PTS gate
  }
  __syncthreads();                                            // B9

  // ---- store current_prior from regs + per-class sums ----
  float a[NCLS];
  #pragma unroll
  for (int cc = 0; cc < NCLS; cc++) a[cc] = 0.f;
  #pragma unroll
  for (int mt = 0; mt < 4; mt++)
    #pragma unroll
    for (int r = 0; r < 4; r++) {
      int R = mt * 16 + quad * 4 + r;
      float vn = val[mt][r] * inv_norm[R];
      out[(p0 + R) * 129 + col] = vn;
      int cls = lbl[R];
      #pragma unroll
      for (int cc = 0; cc < NCLS; cc++) a[cc] += (cls == cc) ? vn : 0.f;
    }
  if (tid < TP) out[(p0 + tid) * 129 + 128] = lbl_eff[tid];
  #pragma unroll
  for (int cc = 0; cc < NCLS; cc++) {
    a[cc] += __shfl_xor(a[cc], 16);
    a[cc] += __shfl_xor(a[cc], 32);
  }
  if (quad == 0)
    #pragma unroll
    for (int cc = 0; cc < NCLS; cc++) atomicAdd(&gsums[cc * 128 + col], a[cc]);

  // ---- last block finalizes the EMA prior (saves a dispatch) ----
  // Ordering: __syncthreads drains vmcnt(0) -> this block's gsums atomics have
  // completed at the device coherence point before the done increment.
  __syncthreads();                                            // B10
  if (tid == 0) {
    int old = atomicAdd(done, 1);
    is_last = (old == NBLK - 1);
  }
  __syncthreads();
  if (!is_last) return;

  float* vbuf = (float*)actbuf;            // actbuf dead; 6656 B needed
  for (int i = tid; i < NCLS * 128; i += 512) {
    float g = atomicAdd(&gsums[i], 0.f);   // coherent device-scope read
    int cls = i >> 7;
    int cnt = counts[cls];
    float mean = g / fmaxf((float)cnt, 1.f);
    float pr = prior[i];
    float cur = (cnt >= 256) ? mean : pr;
    vbuf[i] = 0.999f * pr + 0.001f * cur;
  }
  __syncthreads();
  if (tid < NCLS) {
    float s = 0.f;
    for (int c = 0; c < 128; c++) { float t = vbuf[tid * 128 + c]; s += t * t; }
    invn[tid] = 1.f / fmaxf(sqrtf(s), 1e-12f);
  }
  __syncthreads();
  for (int i = tid; i < NCLS * 128; i += 512)
    out[(long)P_TOTAL * 129 + i] = vbuf[i] * invn[i >> 7];
}

extern "C" void kernel_launch(void* const* d_in, const int* in_sizes, int n_in,
                              void* d_out, int out_size, void* d_ws, size_t ws_size,
                              hipStream_t stream) {
  const float* pos   = (const float*)d_in[0];
  const float* x     = (const float*)d_in[1];
  const int*   y     = (const int*)  d_in[2];
  const float* We1   = (const float*)d_in[3];
  const float* be1   = (const float*)d_in[4];
  const float* We2   = (const float*)d_in[5];
  const float* be2   = (const float*)d_in[6];
  const float* W1    = (const float*)d_in[7];
  const float* b1    = (const float*)d_in[8];
  const float* W2    = (const float*)d_in[9];
  const float* b2    = (const float*)d_in[10];
  const float* prior = (const float*)d_in[11];
  float* out = (float*)d_out;

  char* ws = (char*)d_ws;
  int*    counts = (int*)   (ws + 0);        //    64 B
  float*  gsums  = (float*) (ws + 256);      //  6656 B
  int*    done   = (int*)   (ws + 7168);     //     4 B
  ushort* WT1    = (ushort*)(ws + 8192);     // 16384 B  frag-linear [16 nb][512]
  ushort* WT2    = (ushort*)(ws + 24576);    // 262144 B frag-linear [32 nb][8 kb][512]
  ushort* WT3    = (ushort*)(ws + 286720);   // 262144 B frag-linear [16 nb][16 kb][512]
  ushort* WT4    = (ushort*)(ws + 548864);   // 65536 B  frag-linear [8 nb][8 kb][512]

  hipMemsetAsync(ws, 0, 8192, stream);       // counts + gsums + done
  prep_all_kernel<<<416, 256, 0, stream>>>(We1, We2, W1, W2, y, WT1, WT2, WT3, WT4, counts);
  main_kernel    <<<NBLK, 512, 0, stream>>>(pos, x, y, be1, be2, b1, b2,
                                            WT1, WT2, WT3, WT4, counts, gsums, done, prior, out);
}